// Round 14
// baseline (440.708 us; speedup 1.0000x reference)
//
#include <hip/hip_runtime.h>
#include <hip/hip_bf16.h>

#define N_NODES 100000
#define N_EDGES 320000
#define HID 256
#define NE 128
#define NLAYERS 3

typedef __attribute__((ext_vector_type(8))) short short8;
typedef __attribute__((ext_vector_type(4))) float f32x4;

__device__ inline float bfbits2f(unsigned int b) { return __uint_as_float(b << 16); }

__device__ inline unsigned int pack_bf2(float lo, float hi) {
    __hip_bfloat16 l = __float2bfloat16(lo), h = __float2bfloat16(hi);
    return (unsigned int)*(unsigned short*)&l |
           ((unsigned int)*(unsigned short*)&h << 16);
}

// ---------------------------------------------------------------------------
// Weight prep: fp32 -> bf16, transposed to [n][k].  Also zeroes deg/total.
// ---------------------------------------------------------------------------
__global__ __launch_bounds__(256) void k_prep(
    const float* __restrict__ Wl, const float* __restrict__ Wr,
    const float* __restrict__ W0,
    __hip_bfloat16* __restrict__ Wt, __hip_bfloat16* __restrict__ Wh,
    int* __restrict__ deg, int* __restrict__ total)
{
    int t = blockIdx.x * 256 + threadIdx.x;
    const int total_sage = 3 * 256 * 512;
    if (t < total_sage) {
        int l = t >> 17;
        int rem = t & 131071;
        int n = rem >> 9;
        int k = rem & 511;
        const float* Wsrc = (k < 256) ? (Wl + (size_t)l * 65536)
                                      : (Wr + (size_t)l * 65536);
        Wt[t] = __float2bfloat16(Wsrc[(k & 255) * 256 + n]);
    } else {
        int u = t - total_sage;
        if (u < 65536) {
            int n = u >> 8, k = u & 255;
            Wh[u] = __float2bfloat16(W0[k * 256 + n]);
        }
    }
    if (t < N_NODES) deg[t] = 0;
    if (t == 0) *total = 0;
}

// ---------------------------------------------------------------------------
// Init (vectorized): 32 thr/node, 8B uint2 stores.  Tail ranges: output tail
// and the edge histogram (deg zeroed by k_prep earlier in stream order).
// ---------------------------------------------------------------------------
__global__ __launch_bounds__(256) void k_init(
    const float* __restrict__ node_attr,
    const float* __restrict__ node_emb,
    const float* __restrict__ net_W, const float* __restrict__ net_b,
    const float* __restrict__ dev_W, const float* __restrict__ dev_b,
    const float* __restrict__ pin_emb,
    const int*   __restrict__ node_type,
    const float* __restrict__ y, const float* __restrict__ b1,
    const int*   __restrict__ edge_index, int* __restrict__ deg,
    float* __restrict__ out,
    __hip_bfloat16* __restrict__ x)
{
    int t = blockIdx.x * 256 + threadIdx.x;
    if (t < N_NODES * 32) {
        int n  = t >> 5;
        int c4 = (t & 31) * 4;
        int ty = node_type[n];
        float4 e = *(const float4*)(node_emb + ty * NE + c4);
        float4 a;
        if (ty == 0 || ty == 1) {
            const float* W = (ty == 0) ? net_W : dev_W;
            const float* b = (ty == 0) ? net_b : dev_b;
            a = *(const float4*)(b + c4);
            const float* ar = node_attr + (size_t)n * 17;
            #pragma unroll
            for (int k = 0; k < 17; ++k) {
                float av = ar[k];
                float4 wv = *(const float4*)(W + k * NE + c4);
                a.x += av * wv.x; a.y += av * wv.y;
                a.z += av * wv.z; a.w += av * wv.w;
            }
        } else if (ty == 2) {
            int idx = (int)node_attr[(size_t)n * 17];
            a = *(const float4*)(pin_emb + idx * NE + c4);
        } else {
            a.x = a.y = a.z = a.w = 0.0f;
        }
        uint2 ev = {pack_bf2(e.x, e.y), pack_bf2(e.z, e.w)};
        uint2 av = {pack_bf2(a.x, a.y), pack_bf2(a.z, a.w)};
        *(uint2*)((char*)x + (size_t)n * 512 + c4 * 2)       = ev;
        *(uint2*)((char*)x + (size_t)n * 512 + 256 + c4 * 2) = av;
    } else if (t < N_NODES * 33) {
        int n = t - N_NODES * 32;
        float y0 = y[(size_t)n * 2 + 0];
        float y1 = y[(size_t)n * 2 + 1];
        out[n] = b1[0];
        out[N_NODES + n] = (float)(int)y1;
        out[2 * N_NODES + 2 * n + 0] = y0;
        out[2 * N_NODES + 2 * n + 1] = y1;
    } else {
        int e = t - N_NODES * 33;
        if (e < N_EDGES) atomicAdd(&deg[edge_index[N_EDGES + e]], 1);
    }
}

// ---------------------------------------------------------------------------
// CSR build: scan-free chunk allocation -> fill
// ---------------------------------------------------------------------------
__global__ __launch_bounds__(256) void k_alloc(
    const int* __restrict__ deg, int* __restrict__ off,
    int* __restrict__ cursor, int* __restrict__ total)
{
    int n = blockIdx.x * 256 + threadIdx.x;
    int lane = threadIdx.x & 63;
    int d = (n < N_NODES) ? deg[n] : 0;
    int incl = d;
    #pragma unroll
    for (int o = 1; o < 64; o <<= 1) {
        int v = __shfl_up(incl, o, 64);
        if (lane >= o) incl += v;
    }
    int wtot = __shfl(incl, 63, 64);
    int base = 0;
    if (lane == 63) base = atomicAdd(total, wtot);
    base = __shfl(base, 63, 64);
    if (n < N_NODES) {
        int o = base + incl - d;
        off[n] = o;
        cursor[n] = o;
    }
}

__global__ __launch_bounds__(256) void k_fill(
    const int* __restrict__ edge_index, int* __restrict__ cursor,
    int* __restrict__ slots)
{
    int e = blockIdx.x * 256 + threadIdx.x;
    if (e >= N_EDGES) return;
    int s = edge_index[e];
    int d = edge_index[N_EDGES + e];
    int slot = atomicAdd(&cursor[d], 1);
    slots[slot] = s;
}

// ---------------------------------------------------------------------------
// Gather-mean: 4 nodes per wave, 16 lanes x 32B per node, fp32 accumulate.
// ---------------------------------------------------------------------------
__global__ __launch_bounds__(256) void k_aggregate(
    const __hip_bfloat16* __restrict__ x,
    const int* __restrict__ off, const int* __restrict__ deg,
    const int* __restrict__ slots,
    __hip_bfloat16* __restrict__ agg)
{
    int g = blockIdx.x * 256 + threadIdx.x;
    int wid = g >> 6;
    int lane = g & 63;
    int sub = lane >> 4;
    int l16 = lane & 15;
    int n = wid * 4 + sub;
    bool active = n < N_NODES;
    int o = 0, d = 0;
    if (active) { o = off[n]; d = deg[n]; }
    float acc[16];
    #pragma unroll
    for (int i = 0; i < 16; ++i) acc[i] = 0.0f;
    for (int p = 0; p < d; ++p) {
        int src = slots[o + p];
        const char* rp = (const char*)x + (size_t)src * 512 + l16 * 32;
        uint4 v0 = *(const uint4*)rp;
        uint4 v1 = *(const uint4*)(rp + 16);
        const unsigned int u[8] = {v0.x, v0.y, v0.z, v0.w, v1.x, v1.y, v1.z, v1.w};
        #pragma unroll
        for (int i = 0; i < 8; ++i) {
            acc[2 * i + 0] += bfbits2f(u[i] & 0xffffu);
            acc[2 * i + 1] += __uint_as_float(u[i] & 0xffff0000u);
        }
    }
    if (active) {
        float rs = 1.0f / fmaxf((float)d, 1.0f);
        unsigned int w[8];
        #pragma unroll
        for (int i = 0; i < 8; ++i)
            w[i] = pack_bf2(acc[2 * i + 0] * rs, acc[2 * i + 1] * rs);
        uint4 o0 = {w[0], w[1], w[2], w[3]};
        uint4 o1 = {w[4], w[5], w[6], w[7]};
        char* op = (char*)agg + (size_t)n * 512 + l16 * 32;
        *(uint4*)op = o0;
        *(uint4*)(op + 16) = o1;
    }
}

// ---------------------------------------------------------------------------
// MFMA layer, high-N-reuse geometry (LDS-read pressure was the real floor:
// each ds_read_b128 A-frag previously fed only 2 MFMA; per-CU LDS ~1500cyc
// vs ~300cyc matrix pipe per step.  Now each A-frag feeds 4 MFMA).
// Block 256 thr = 4 waves; tile BM=64 x BN=256; wave owns 64 cols (4 B-frags).
// 3-buffer LDS (3x8KB) + 32KB epilogue union -> 4+ blocks/CU; counted-vmcnt
// single-barrier schedule (queue [stage(s)x2, B(s)x8, stage(s+1)x2] -> vmcnt(2)).
// SAGE: Out = relu([Agg|X] @ Wt^T + bias)   (K=512)
// HEAD: Pred += relu(X @ Wh^T + bias) . W1  (K=256; block owns rows -> plain RMW)
// ---------------------------------------------------------------------------
template <bool SAGE>
__global__ __launch_bounds__(256) void k_mfma(
    const __hip_bfloat16* __restrict__ Agg,
    const __hip_bfloat16* __restrict__ X,
    const __hip_bfloat16* __restrict__ Wt,
    const float* __restrict__ bias,
    const float* __restrict__ W1,
    __hip_bfloat16* __restrict__ Out,
    float* __restrict__ Pred)
{
    __shared__ char smem[32768];    // staging 3x8KB; SAGE epilogue 64x256 bf16

    const int tid  = threadIdx.x;
    const int w    = tid >> 6, lane = tid & 63;
    const int l15  = lane & 15, lg = lane >> 4;
    const int row0 = blockIdx.x * 64;
    const int col0 = w * 64;
    const int KT     = SAGE ? 512 : 256;
    const int nsteps = SAGE ? 8 : 4;

    f32x4 acc[4][4];
    #pragma unroll
    for (int i = 0; i < 4; ++i)
        #pragma unroll
        for (int n = 0; n < 4; ++n) acc[i][n] = (f32x4)0.0f;

    // staging: 256 thr x 16B x 2 issues = 8KB = 64 rows x 128B
    const int srow   = tid >> 3;     // 0..31 (+32 on issue 1)
    const int schunk = tid & 7;

    auto stage = [&](int s) {
        const int b = s % 3;
        const char* base;
        int k0;
        if (SAGE && s < 4) { base = (const char*)Agg; k0 = s * 64; }
        else               { base = (const char*)X;   k0 = (SAGE ? s - 4 : s) * 64; }
        #pragma unroll
        for (int issue = 0; issue < 2; ++issue) {
            int row  = srow + issue * 32;
            int grow = row0 + row;
            if (grow >= N_NODES) grow = N_NODES - 1;
            const char* gp = base + (size_t)grow * 512 + (size_t)k0 * 2
                           + ((schunk ^ (row & 7)) << 4);      // inverse swizzle
            const char* lp = smem + b * 8192 + issue * 4096 + tid * 16;  // linear
            __builtin_amdgcn_global_load_lds(
                (const __attribute__((address_space(1))) void*)gp,
                (__attribute__((address_space(3))) void*)lp, 16, 0, 0);
        }
    };

    auto loadB = [&](int s, short8 (&bb)[2][4]) {
        #pragma unroll
        for (int h = 0; h < 2; ++h)
            #pragma unroll
            for (int n = 0; n < 4; ++n) {
                int c = col0 + n * 16 + l15;
                bb[h][n] = *(const short8*)(Wt + (size_t)c * KT + s * 64 + h * 32 + 8 * lg);
            }
    };

    auto do_step = [&](int s, bool last, short8 (&bcur)[2][4], short8 (&bnxt)[2][4]) {
        const int b = s % 3;
        if (last) asm volatile("s_waitcnt vmcnt(0)" ::: "memory");
        else      asm volatile("s_waitcnt vmcnt(2)" ::: "memory");
        __builtin_amdgcn_sched_barrier(0);
        __builtin_amdgcn_s_barrier();
        __builtin_amdgcn_sched_barrier(0);
        if (!last) loadB(s + 1, bnxt);          // B prefetch for next step
        if (s + 2 < nsteps) stage(s + 2);       // 2-step-ahead A staging
        #pragma unroll
        for (int h = 0; h < 2; ++h) {
            #pragma unroll
            for (int i = 0; i < 4; ++i) {
                int r = i * 16 + l15;
                short8 a = *(const short8*)(smem + b * 8192 + r * 128
                                            + (((lg + 4 * h) ^ (r & 7)) << 4));
                #pragma unroll
                for (int n = 0; n < 4; ++n)
                    acc[i][n] = __builtin_amdgcn_mfma_f32_16x16x32_bf16(
                        a, bcur[h][n], acc[i][n], 0, 0, 0);
            }
        }
    };

    short8 b0[2][4], b1r[2][4];
    loadB(0, b0);       // queue: [B0 x8, st0 x2, st1 x2] -> vmcnt(2) at step 0 ok
    stage(0);
    stage(1);
    if (SAGE) {
        do_step(0, false, b0, b1r);
        do_step(1, false, b1r, b0);
        do_step(2, false, b0, b1r);
        do_step(3, false, b1r, b0);
        do_step(4, false, b0, b1r);
        do_step(5, false, b1r, b0);
        do_step(6, false, b0, b1r);
        do_step(7, true,  b1r, b0);
    } else {
        do_step(0, false, b0, b1r);
        do_step(1, false, b1r, b0);
        do_step(2, false, b0, b1r);
        do_step(3, true,  b1r, b0);
    }

    if (SAGE) {
        __syncthreads();   // all waves done with staging before epilogue reuse
        __hip_bfloat16* lo = (__hip_bfloat16*)smem;   // 64 x 256 bf16 = 32KB
        #pragma unroll
        for (int n = 0; n < 4; ++n) {
            int c = col0 + n * 16 + l15;
            float bv = bias[c];
            #pragma unroll
            for (int i = 0; i < 4; ++i)
                #pragma unroll
                for (int r = 0; r < 4; ++r) {
                    int rl = i * 16 + lg * 4 + r;
                    lo[rl * 256 + c] = __float2bfloat16(fmaxf(acc[i][n][r] + bv, 0.0f));
                }
        }
        __syncthreads();
        #pragma unroll
        for (int q = 0; q < 8; ++q) {
            int chunk = tid + q * 256;      // 2048 x 16B = 64 rows x 512B
            int rl = chunk >> 5, cc = chunk & 31;
            int grow = row0 + rl;
            if (grow < N_NODES)
                *(uint4*)((char*)Out + (size_t)grow * 512 + cc * 16) =
                    *(const uint4*)((const char*)smem + rl * 512 + cc * 16);
        }
    } else {
        __syncthreads();
        float* part = (float*)smem;     // [64][4]
        #pragma unroll
        for (int i = 0; i < 4; ++i) {
            float p[4];
            #pragma unroll
            for (int r = 0; r < 4; ++r) p[r] = 0.0f;
            #pragma unroll
            for (int n = 0; n < 4; ++n) {
                int cg = col0 + n * 16 + l15;
                float bv = bias[cg];
                float wv = W1[cg];
                #pragma unroll
                for (int r = 0; r < 4; ++r)
                    p[r] += fmaxf(acc[i][n][r] + bv, 0.0f) * wv;
            }
            #pragma unroll
            for (int r = 0; r < 4; ++r) {
                float s = p[r];
                #pragma unroll
                for (int m = 1; m < 16; m <<= 1) s += __shfl_xor(s, m, 64);
                if (l15 == 0)
                    part[(i * 16 + lg * 4 + r) * 4 + w] = s;
            }
        }
        __syncthreads();
        if (tid < 64) {
            int grow = row0 + tid;
            if (grow < N_NODES) {
                // Pred[grow] pre-initialized to b1 by k_init; block owns row.
                float s = Pred[grow];
                #pragma unroll
                for (int j = 0; j < 4; ++j) s += part[tid * 4 + j];
                Pred[grow] = s;
            }
        }
    }
}

extern "C" void kernel_launch(void* const* d_in, const int* in_sizes, int n_in,
                              void* d_out, int out_size, void* d_ws, size_t ws_size,
                              hipStream_t stream) {
    const float* node_attr = (const float*)d_in[0];
    const float* y         = (const float*)d_in[1];
    const float* node_emb  = (const float*)d_in[2];
    const float* net_W     = (const float*)d_in[4];
    const float* net_b     = (const float*)d_in[5];
    const float* dev_W     = (const float*)d_in[6];
    const float* dev_b     = (const float*)d_in[7];
    const float* pin_emb   = (const float*)d_in[8];
    const float* sage_Wl   = (const float*)d_in[9];
    const float* sage_bl   = (const float*)d_in[10];
    const float* sage_Wr   = (const float*)d_in[11];
    const float* head_W0   = (const float*)d_in[12];
    const float* head_b0   = (const float*)d_in[13];
    const float* head_W1   = (const float*)d_in[14];
    const float* head_b1   = (const float*)d_in[15];
    const int*   node_type = (const int*)d_in[16];
    const int*   edge_idx  = (const int*)d_in[18];
    float* out = (float*)d_out;

    const size_t xelems = (size_t)N_NODES * HID;
    char* p = (char*)d_ws;
    __hip_bfloat16* x0  = (__hip_bfloat16*)p;  p += xelems * 2;
    __hip_bfloat16* x1  = (__hip_bfloat16*)p;  p += xelems * 2;
    __hip_bfloat16* agg = (__hip_bfloat16*)p;  p += xelems * 2;
    __hip_bfloat16* Wt  = (__hip_bfloat16*)p;  p += (size_t)3 * 256 * 512 * 2;
    __hip_bfloat16* Wh  = (__hip_bfloat16*)p;  p += (size_t)256 * 256 * 2;
    int* deg    = (int*)p; p += N_NODES * 4;
    int* off    = (int*)p; p += N_NODES * 4;
    int* cursor = (int*)p; p += N_NODES * 4;
    int* slots  = (int*)p; p += N_EDGES * 4;
    int* total  = (int*)p; p += 16;

    k_prep<<<(3 * 131072 + 65536 + 255) / 256, 256, 0, stream>>>(
        sage_Wl, sage_Wr, head_W0, Wt, Wh, deg, total);
    k_init<<<(N_NODES * 33 + N_EDGES + 255) / 256, 256, 0, stream>>>(
        node_attr, node_emb, net_W, net_b, dev_W, dev_b, pin_emb, node_type,
        y, head_b1, edge_idx, deg, out, x0);
    k_alloc<<<(N_NODES + 255) / 256, 256, 0, stream>>>(deg, off, cursor, total);
    k_fill<<<(N_EDGES + 255) / 256, 256, 0, stream>>>(edge_idx, cursor, slots);

    const int gemm_grid = (N_NODES + 63) / 64;      // 1563 blocks, 4 waves
    __hip_bfloat16* xcur = x0;
    __hip_bfloat16* xalt = x1;
    for (int l = 0; l < NLAYERS; ++l) {
        k_aggregate<<<(N_NODES / 4 * 64 + 255) / 256, 256, 0, stream>>>(
            xcur, off, deg, slots, agg);
        k_mfma<true><<<gemm_grid, 256, 0, stream>>>(
            agg, xcur, Wt + (size_t)l * 131072,
            sage_bl + (size_t)l * HID, nullptr, xalt, nullptr);
        __hip_bfloat16* t = xcur; xcur = xalt; xalt = t;
    }
    k_mfma<false><<<gemm_grid, 256, 0, stream>>>(
        xcur, xcur, Wh, head_b0, head_W1, nullptr, out);
}

// Round 15
// 359.815 us; speedup vs baseline: 1.2248x; 1.2248x over previous
//
#include <hip/hip_runtime.h>
#include <hip/hip_bf16.h>
#include <hip/hip_fp8.h>

#define N_NODES 100000
#define N_EDGES 320000
#define HID 256
#define NE 128

typedef __attribute__((ext_vector_type(8))) short short8;
typedef __attribute__((ext_vector_type(4))) float f32x4;
typedef long long i64v;

__device__ inline unsigned char f2fp8(float f) { return __hip_fp8_e4m3(f).__x; }
__device__ inline float fp82f(unsigned char b) {
    __hip_fp8_e4m3 h; h.__x = b; return (float)h;
}
__device__ inline unsigned int pack_fp8x4(float a, float b, float c, float d) {
    return (unsigned)f2fp8(a) | ((unsigned)f2fp8(b) << 8) |
           ((unsigned)f2fp8(c) << 16) | ((unsigned)f2fp8(d) << 24);
}

// ---------------------------------------------------------------------------
// Weight prep: sage weights fp32 -> fp8 [n][k]; head W0 -> bf16 [n][k].
// Also zeroes deg/total.
// ---------------------------------------------------------------------------
__global__ __launch_bounds__(256) void k_prep(
    const float* __restrict__ Wl, const float* __restrict__ Wr,
    const float* __restrict__ W0,
    unsigned char* __restrict__ Wt8, __hip_bfloat16* __restrict__ Wh,
    int* __restrict__ deg, int* __restrict__ total)
{
    int t = blockIdx.x * 256 + threadIdx.x;
    const int total_sage = 3 * 256 * 512;
    if (t < total_sage) {
        int l = t >> 17;
        int rem = t & 131071;
        int n = rem >> 9;
        int k = rem & 511;
        const float* Wsrc = (k < 256) ? (Wl + (size_t)l * 65536)
                                      : (Wr + (size_t)l * 65536);
        Wt8[t] = f2fp8(Wsrc[(k & 255) * 256 + n]);
    } else {
        int u = t - total_sage;
        if (u < 65536) {
            int n = u >> 8, k = u & 255;
            Wh[u] = __float2bfloat16(W0[k * 256 + n]);
        }
    }
    if (t < N_NODES) deg[t] = 0;
    if (t == 0) *total = 0;
}

// ---------------------------------------------------------------------------
// Init: x0 in fp8 (row = 256B: [emb 0..127 | attr 128..255]).
// 16 thr/node x 8 cols, uint2 stores.  Tail ranges: output tail + histogram.
// ---------------------------------------------------------------------------
__global__ __launch_bounds__(256) void k_init(
    const float* __restrict__ node_attr,
    const float* __restrict__ node_emb,
    const float* __restrict__ net_W, const float* __restrict__ net_b,
    const float* __restrict__ dev_W, const float* __restrict__ dev_b,
    const float* __restrict__ pin_emb,
    const int*   __restrict__ node_type,
    const float* __restrict__ y, const float* __restrict__ b1,
    const int*   __restrict__ edge_index, int* __restrict__ deg,
    float* __restrict__ out,
    unsigned char* __restrict__ x)
{
    int t = blockIdx.x * 256 + threadIdx.x;
    if (t < N_NODES * 16) {
        int n  = t >> 4;
        int c8 = (t & 15) * 8;
        int ty = node_type[n];
        float4 e0 = *(const float4*)(node_emb + ty * NE + c8);
        float4 e1 = *(const float4*)(node_emb + ty * NE + c8 + 4);
        float4 a0, a1;
        if (ty == 0 || ty == 1) {
            const float* W = (ty == 0) ? net_W : dev_W;
            const float* b = (ty == 0) ? net_b : dev_b;
            a0 = *(const float4*)(b + c8);
            a1 = *(const float4*)(b + c8 + 4);
            const float* ar = node_attr + (size_t)n * 17;
            #pragma unroll
            for (int k = 0; k < 17; ++k) {
                float av = ar[k];
                float4 w0 = *(const float4*)(W + k * NE + c8);
                float4 w1 = *(const float4*)(W + k * NE + c8 + 4);
                a0.x += av * w0.x; a0.y += av * w0.y;
                a0.z += av * w0.z; a0.w += av * w0.w;
                a1.x += av * w1.x; a1.y += av * w1.y;
                a1.z += av * w1.z; a1.w += av * w1.w;
            }
        } else if (ty == 2) {
            int idx = (int)node_attr[(size_t)n * 17];
            a0 = *(const float4*)(pin_emb + idx * NE + c8);
            a1 = *(const float4*)(pin_emb + idx * NE + c8 + 4);
        } else {
            a0.x = a0.y = a0.z = a0.w = 0.0f;
            a1 = a0;
        }
        uint2 ev = {pack_fp8x4(e0.x, e0.y, e0.z, e0.w),
                    pack_fp8x4(e1.x, e1.y, e1.z, e1.w)};
        uint2 av = {pack_fp8x4(a0.x, a0.y, a0.z, a0.w),
                    pack_fp8x4(a1.x, a1.y, a1.z, a1.w)};
        *(uint2*)(x + (size_t)n * 256 + c8)       = ev;
        *(uint2*)(x + (size_t)n * 256 + 128 + c8) = av;
    } else if (t < N_NODES * 17) {
        int n = t - N_NODES * 16;
        float y0 = y[(size_t)n * 2 + 0];
        float y1 = y[(size_t)n * 2 + 1];
        out[n] = b1[0];
        out[N_NODES + n] = (float)(int)y1;
        out[2 * N_NODES + 2 * n + 0] = y0;
        out[2 * N_NODES + 2 * n + 1] = y1;
    } else {
        int e = t - N_NODES * 17;
        if (e < N_EDGES) atomicAdd(&deg[edge_index[N_EDGES + e]], 1);
    }
}

// ---------------------------------------------------------------------------
// CSR build: scan-free chunk allocation -> fill
// ---------------------------------------------------------------------------
__global__ __launch_bounds__(256) void k_alloc(
    const int* __restrict__ deg, int* __restrict__ off,
    int* __restrict__ cursor, int* __restrict__ total)
{
    int n = blockIdx.x * 256 + threadIdx.x;
    int lane = threadIdx.x & 63;
    int d = (n < N_NODES) ? deg[n] : 0;
    int incl = d;
    #pragma unroll
    for (int o = 1; o < 64; o <<= 1) {
        int v = __shfl_up(incl, o, 64);
        if (lane >= o) incl += v;
    }
    int wtot = __shfl(incl, 63, 64);
    int base = 0;
    if (lane == 63) base = atomicAdd(total, wtot);
    base = __shfl(base, 63, 64);
    if (n < N_NODES) {
        int o = base + incl - d;
        off[n] = o;
        cursor[n] = o;
    }
}

__global__ __launch_bounds__(256) void k_fill(
    const int* __restrict__ edge_index, int* __restrict__ cursor,
    int* __restrict__ slots)
{
    int e = blockIdx.x * 256 + threadIdx.x;
    if (e >= N_EDGES) return;
    int s = edge_index[e];
    int d = edge_index[N_EDGES + e];
    int slot = atomicAdd(&cursor[d], 1);
    slots[slot] = s;
}

// ---------------------------------------------------------------------------
// Gather-mean over fp8 rows (256B): 4 nodes/wave, 16 lanes x 16B, fp32 acc.
// ---------------------------------------------------------------------------
__global__ __launch_bounds__(256) void k_aggregate(
    const unsigned char* __restrict__ x,
    const int* __restrict__ off, const int* __restrict__ deg,
    const int* __restrict__ slots,
    unsigned char* __restrict__ agg)
{
    int g = blockIdx.x * 256 + threadIdx.x;
    int wid = g >> 6;
    int lane = g & 63;
    int sub = lane >> 4;
    int l16 = lane & 15;
    int n = wid * 4 + sub;
    bool active = n < N_NODES;
    int o = 0, d = 0;
    if (active) { o = off[n]; d = deg[n]; }
    float acc[16];
    #pragma unroll
    for (int i = 0; i < 16; ++i) acc[i] = 0.0f;
    for (int p = 0; p < d; ++p) {
        int src = slots[o + p];
        uint4 v = *(const uint4*)(x + (size_t)src * 256 + l16 * 16);
        unsigned int uu[4] = {v.x, v.y, v.z, v.w};
        #pragma unroll
        for (int j = 0; j < 4; ++j)
            #pragma unroll
            for (int b = 0; b < 4; ++b)
                acc[j * 4 + b] += fp82f((uu[j] >> (8 * b)) & 0xffu);
    }
    if (active) {
        float rs = 1.0f / fmaxf((float)d, 1.0f);
        uint4 ov;
        ov.x = pack_fp8x4(acc[0] * rs,  acc[1] * rs,  acc[2] * rs,  acc[3] * rs);
        ov.y = pack_fp8x4(acc[4] * rs,  acc[5] * rs,  acc[6] * rs,  acc[7] * rs);
        ov.z = pack_fp8x4(acc[8] * rs,  acc[9] * rs,  acc[10] * rs, acc[11] * rs);
        ov.w = pack_fp8x4(acc[12] * rs, acc[13] * rs, acc[14] * rs, acc[15] * rs);
        *(uint4*)(agg + (size_t)n * 256 + l16 * 16) = ov;
    }
}

// ---------------------------------------------------------------------------
// SAGE layer, fp8 MFMA (R10 skeleton: 3-buffer LDS, single barrier/step,
// counted vmcnt; 512 thr = 8 waves x 32 cols; tile 128x256, BK=64 elems=64B).
// Staging: 512 thr x 16B = 8KB/step; 16B-granule swizzle c16^(row&3)
// (pre-swizzled global source, linear LDS dest, swizzled 8B ds_read ->
// every bank at the 4-access minimum for b64).  Steady wait vmcnt(1)
// (queue [stage(s), B(s)x4, stage(s+1)]), last step vmcnt(0).
// A = [Agg8 | X8] (K=512 fp8); B = Wt8 [n][k] fp8.
// BF16OUT=false: Out fp8 (row 256B); true: Out bf16 (row 512B, for head).
// ---------------------------------------------------------------------------
template <bool BF16OUT>
__global__ __launch_bounds__(512, 4) void k_sage(
    const unsigned char* __restrict__ Agg8,
    const unsigned char* __restrict__ X8,
    const unsigned char* __restrict__ Wt8,
    const float* __restrict__ bias,
    void* __restrict__ OutP)
{
    __shared__ char smem[32768];    // staging 3x8KB; epilogue tile reuse

    const int tid  = threadIdx.x;
    const int w    = tid >> 6, lane = tid & 63;
    const int l15  = lane & 15, lg = lane >> 4;
    const int row0 = blockIdx.x * 128;

    f32x4 acc[8][2];
    #pragma unroll
    for (int i = 0; i < 8; ++i)
        #pragma unroll
        for (int n = 0; n < 2; ++n) acc[i][n] = (f32x4)0.0f;

    // staging: 4 thr/row x 16B; row = tid>>2 (0..127), c16 = tid&3
    const int srow = tid >> 2;
    const int c16s = tid & 3;
    int sgrow = row0 + srow; if (sgrow >= N_NODES) sgrow = N_NODES - 1;

    auto stage = [&](int s) {
        const int b = s % 3;
        const unsigned char* base = (s < 4) ? Agg8 : X8;
        int k0 = (s & 3) * 64;
        const unsigned char* gp = base + (size_t)sgrow * 256 + k0
                                + ((c16s ^ (srow & 3)) << 4);   // inverse swizzle
        const char* lp = smem + b * 8192 + tid * 16;            // linear dest
        __builtin_amdgcn_global_load_lds(
            (const __attribute__((address_space(1))) void*)gp,
            (__attribute__((address_space(3))) void*)lp, 16, 0, 0);
    };

    auto loadB = [&](int s, i64v (&bb)[2][2]) {
        #pragma unroll
        for (int h = 0; h < 2; ++h)
            #pragma unroll
            for (int n = 0; n < 2; ++n) {
                int c = w * 32 + n * 16 + l15;
                bb[h][n] = *(const i64v*)(Wt8 + (size_t)c * 512 + s * 64
                                          + h * 32 + lg * 8);
            }
    };

    auto do_step = [&](int s, bool last, i64v (&bcur)[2][2], i64v (&bnxt)[2][2]) {
        const int b = s % 3;
        if (last) asm volatile("s_waitcnt vmcnt(0)" ::: "memory");
        else      asm volatile("s_waitcnt vmcnt(1)" ::: "memory");
        __builtin_amdgcn_sched_barrier(0);
        __builtin_amdgcn_s_barrier();
        __builtin_amdgcn_sched_barrier(0);
        if (!last) loadB(s + 1, bnxt);          // B prefetch for next step
        if (s + 2 < 8) stage(s + 2);            // 2-step-ahead A staging
        #pragma unroll
        for (int h = 0; h < 2; ++h) {
            const int c8 = h * 4 + lg;          // 8B chunk index 0..7
            #pragma unroll
            for (int i = 0; i < 8; ++i) {
                int r = i * 16 + l15;
                i64v a = *(const i64v*)(smem + b * 8192 + r * 64
                            + ((((c8 >> 1) ^ (r & 3)) << 4) | ((c8 & 1) << 3)));
                acc[i][0] = __builtin_amdgcn_mfma_f32_16x16x32_fp8_fp8(
                    a, bcur[h][0], acc[i][0], 0, 0, 0);
                acc[i][1] = __builtin_amdgcn_mfma_f32_16x16x32_fp8_fp8(
                    a, bcur[h][1], acc[i][1], 0, 0, 0);
            }
        }
    };

    i64v b0[2][2], b1r[2][2];
    loadB(0, b0);       // queue: [B0 x4, st0, st1] -> vmcnt(1) at step 0 ok
    stage(0);
    stage(1);
    do_step(0, false, b0, b1r);
    do_step(1, false, b1r, b0);
    do_step(2, false, b0, b1r);
    do_step(3, false, b1r, b0);
    do_step(4, false, b0, b1r);
    do_step(5, false, b1r, b0);
    do_step(6, false, b0, b1r);
    do_step(7, true,  b1r, b0);

    __syncthreads();   // all waves done with staging before epilogue reuse
    if (BF16OUT) {
        __hip_bfloat16* Out = (__hip_bfloat16*)OutP;
        __hip_bfloat16* lo = (__hip_bfloat16*)smem;   // 64x256 bf16 = 32KB half
        #pragma unroll
        for (int hh = 0; hh < 2; ++hh) {
            #pragma unroll
            for (int n = 0; n < 2; ++n) {
                int c = w * 32 + n * 16 + l15;
                float bv = bias[c];
                #pragma unroll
                for (int i2 = 0; i2 < 4; ++i2) {
                    int i = hh * 4 + i2;
                    #pragma unroll
                    for (int r = 0; r < 4; ++r) {
                        int rl = i2 * 16 + lg * 4 + r;
                        lo[rl * 256 + c] =
                            __float2bfloat16(fmaxf(acc[i][n][r] + bv, 0.0f));
                    }
                }
            }
            __syncthreads();
            #pragma unroll
            for (int q = 0; q < 4; ++q) {
                int chunk = tid + q * 512;      // 2048 x 16B = 64 rows x 512B
                int rl = chunk >> 5, cc = chunk & 31;
                int grow = row0 + hh * 64 + rl;
                if (grow < N_NODES)
                    *(uint4*)((char*)Out + (size_t)grow * 512 + cc * 16) =
                        *(const uint4*)((const char*)smem + rl * 512 + cc * 16);
            }
            __syncthreads();
        }
    } else {
        unsigned char* Out = (unsigned char*)OutP;
        unsigned char* lo = (unsigned char*)smem;     // 64x256 fp8 = 16KB half
        #pragma unroll
        for (int hh = 0; hh < 2; ++hh) {
            #pragma unroll
            for (int n = 0; n < 2; ++n) {
                int c = w * 32 + n * 16 + l15;
                float bv = bias[c];
                #pragma unroll
                for (int i2 = 0; i2 < 4; ++i2) {
                    int i = hh * 4 + i2;
                    #pragma unroll
                    for (int r = 0; r < 4; ++r) {
                        int rl = i2 * 16 + lg * 4 + r;
                        lo[rl * 256 + c] = f2fp8(fmaxf(acc[i][n][r] + bv, 0.0f));
                    }
                }
            }
            __syncthreads();
            #pragma unroll
            for (int q = 0; q < 2; ++q) {
                int chunk = tid + q * 512;      // 1024 x 16B = 64 rows x 256B
                int rl = chunk >> 4, cc = chunk & 15;
                int grow = row0 + hh * 64 + rl;
                if (grow < N_NODES)
                    *(uint4*)(Out + (size_t)grow * 256 + cc * 16) =
                        *(const uint4*)((const char*)smem + rl * 256 + cc * 16);
            }
            __syncthreads();
        }
    }
}

// ---------------------------------------------------------------------------
// HEAD (bf16, R10-proven): Pred += relu(X @ Wh^T + b0) . W1
// (K=256; Pred pre-init b1; atomicAdd partials)
// ---------------------------------------------------------------------------
__global__ __launch_bounds__(512, 4) void k_head(
    const __hip_bfloat16* __restrict__ X,
    const __hip_bfloat16* __restrict__ Wt,
    const float* __restrict__ bias,
    const float* __restrict__ W1,
    float* __restrict__ Pred)
{
    __shared__ char smem[49152];    // 3 x 16KB staging

    const int tid  = threadIdx.x;
    const int w    = tid >> 6, lane = tid & 63;
    const int l15  = lane & 15, lg = lane >> 4;
    const int row0 = blockIdx.x * 128;

    f32x4 acc[8][2];
    #pragma unroll
    for (int i = 0; i < 8; ++i)
        #pragma unroll
        for (int n = 0; n < 2; ++n) acc[i][n] = (f32x4)0.0f;

    const int srow   = tid >> 3;
    const int schunk = tid & 7;

    auto stage = [&](int s) {
        const int b = s % 3;
        #pragma unroll
        for (int issue = 0; issue < 2; ++issue) {
            int row  = srow + issue * 64;
            int grow = row0 + row;
            if (grow >= N_NODES) grow = N_NODES - 1;
            const char* gp = (const char*)X + (size_t)grow * 512 + s * 128
                           + ((schunk ^ (row & 7)) << 4);
            const char* lp = smem + b * 16384 + issue * 8192 + tid * 16;
            __builtin_amdgcn_global_load_lds(
                (const __attribute__((address_space(1))) void*)gp,
                (__attribute__((address_space(3))) void*)lp, 16, 0, 0);
        }
    };

    auto loadB = [&](int s, short8 (&bb)[2][2]) {
        #pragma unroll
        for (int h = 0; h < 2; ++h)
            #pragma unroll
            for (int n = 0; n < 2; ++n) {
                int c = w * 32 + n * 16 + l15;
                bb[h][n] = *(const short8*)(Wt + (size_t)c * 256 + s * 64
                                            + h * 32 + 8 * lg);
            }
    };

    auto do_step = [&](int s, bool last, short8 (&bcur)[2][2], short8 (&bnxt)[2][2]) {
        const int b = s % 3;
        if (last) asm volatile("s_waitcnt vmcnt(0)" ::: "memory");
        else      asm volatile("s_waitcnt vmcnt(2)" ::: "memory");
        __builtin_amdgcn_sched_barrier(0);
        __builtin_amdgcn_s_barrier();
        __builtin_amdgcn_sched_barrier(0);
        if (!last) loadB(s + 1, bnxt);
        if (s + 2 < 4) stage(s + 2);
        #pragma unroll
        for (int h = 0; h < 2; ++h) {
            #pragma unroll
            for (int i = 0; i < 8; ++i) {
                int r = i * 16 + l15;
                short8 a = *(const short8*)(smem + b * 16384 + r * 128
                                + (((lg + 4 * h) ^ (r & 7)) << 4));
                acc[i][0] = __builtin_amdgcn_mfma_f32_16x16x32_bf16(
                    a, bcur[h][0], acc[i][0], 0, 0, 0);
                acc[i][1] = __builtin_amdgcn_mfma_f32_16x16x32_bf16(
                    a, bcur[h][1], acc[i][1], 0, 0, 0);
            }
        }
    };

    short8 b0[2][2], b1r[2][2];
    loadB(0, b0);
    stage(0);
    stage(1);
    do_step(0, false, b0, b1r);
    do_step(1, false, b1r, b0);
    do_step(2, false, b0, b1r);
    do_step(3, true,  b1r, b0);

    #pragma unroll
    for (int i = 0; i < 8; ++i) {
        float p[4];
        #pragma unroll
        for (int r = 0; r < 4; ++r) p[r] = 0.0f;
        #pragma unroll
        for (int n = 0; n < 2; ++n) {
            int cg = w * 32 + n * 16 + l15;
            float bv = bias[cg];
            float wv = W1[cg];
            #pragma unroll
            for (int r = 0; r < 4; ++r)
                p[r] += fmaxf(acc[i][n][r] + bv, 0.0f) * wv;
        }
        #pragma unroll
        for (int r = 0; r < 4; ++r) {
            float s = p[r];
            #pragma unroll
            for (int m = 1; m < 16; m <<= 1) s += __shfl_xor(s, m, 64);
            if (l15 == 0) {
                int row = row0 + i * 16 + lg * 4 + r;
                if (row < N_NODES) atomicAdd(&Pred[row], s);
            }
        }
    }
}

extern "C" void kernel_launch(void* const* d_in, const int* in_sizes, int n_in,
                              void* d_out, int out_size, void* d_ws, size_t ws_size,
                              hipStream_t stream) {
    const float* node_attr = (const float*)d_in[0];
    const float* y         = (const float*)d_in[1];
    const float* node_emb  = (const float*)d_in[2];
    const float* net_W     = (const float*)d_in[4];
    const float* net_b     = (const float*)d_in[5];
    const float* dev_W     = (const float*)d_in[6];
    const float* dev_b     = (const float*)d_in[7];
    const float* pin_emb   = (const float*)d_in[8];
    const float* sage_Wl   = (const float*)d_in[9];
    const float* sage_bl   = (const float*)d_in[10];
    const float* sage_Wr   = (const float*)d_in[11];
    const float* head_W0   = (const float*)d_in[12];
    const float* head_b0   = (const float*)d_in[13];
    const float* head_W1   = (const float*)d_in[14];
    const float* head_b1   = (const float*)d_in[15];
    const int*   node_type = (const int*)d_in[16];
    const int*   edge_idx  = (const int*)d_in[18];
    float* out = (float*)d_out;

    const size_t x8b = (size_t)N_NODES * 256;       // fp8 row bytes
    char* p = (char*)d_ws;
    unsigned char* x0   = (unsigned char*)p;  p += x8b;
    unsigned char* x1   = (unsigned char*)p;  p += x8b;
    unsigned char* agg8 = (unsigned char*)p;  p += x8b;
    __hip_bfloat16* x3bf = (__hip_bfloat16*)p; p += (size_t)N_NODES * 512;
    unsigned char* Wt8  = (unsigned char*)p;  p += (size_t)3 * 256 * 512;
    __hip_bfloat16* Wh  = (__hip_bfloat16*)p; p += (size_t)256 * 256 * 2;
    int* deg    = (int*)p; p += N_NODES * 4;
    int* off    = (int*)p; p += N_NODES * 4;
    int* cursor = (int*)p; p += N_NODES * 4;
    int* slots  = (int*)p; p += N_EDGES * 4;
    int* total  = (int*)p; p += 16;

    k_prep<<<(3 * 131072 + 65536 + 255) / 256, 256, 0, stream>>>(
        sage_Wl, sage_Wr, head_W0, Wt8, Wh, deg, total);
    k_init<<<(N_NODES * 17 + N_EDGES + 255) / 256, 256, 0, stream>>>(
        node_attr, node_emb, net_W, net_b, dev_W, dev_b, pin_emb, node_type,
        y, head_b1, edge_idx, deg, out, x0);
    k_alloc<<<(N_NODES + 255) / 256, 256, 0, stream>>>(deg, off, cursor, total);
    k_fill<<<(N_EDGES + 255) / 256, 256, 0, stream>>>(edge_idx, cursor, slots);

    const int agg_grid  = (N_NODES / 4 * 64 + 255) / 256;
    const int gemm_grid = (N_NODES + 127) / 128;
    // layer 1
    k_aggregate<<<agg_grid, 256, 0, stream>>>(x0, off, deg, slots, agg8);
    k_sage<false><<<gemm_grid, 512, 0, stream>>>(
        agg8, x0, Wt8, sage_bl, x1);
    // layer 2
    k_aggregate<<<agg_grid, 256, 0, stream>>>(x1, off, deg, slots, agg8);
    k_sage<false><<<gemm_grid, 512, 0, stream>>>(
        agg8, x1, Wt8 + 131072, sage_bl + HID, x0);
    // layer 3 (bf16 out for head)
    k_aggregate<<<agg_grid, 256, 0, stream>>>(x0, off, deg, slots, agg8);
    k_sage<true><<<gemm_grid, 512, 0, stream>>>(
        agg8, x0, Wt8 + 262144, sage_bl + 2 * HID, x3bf);
    // head
    k_head<<<gemm_grid, 512, 0, stream>>>(x3bf, Wh, head_b0, head_W1, out);
}

// Round 16
// 338.803 us; speedup vs baseline: 1.3008x; 1.0620x over previous
//
#include <hip/hip_runtime.h>
#include <hip/hip_bf16.h>
#include <hip/hip_fp8.h>

#define N_NODES 100000
#define N_EDGES 320000
#define HID 256
#define NE 128

typedef __attribute__((ext_vector_type(4))) float f32x4;
typedef long long i64v;

__device__ inline unsigned char f2fp8(float f) { return __hip_fp8_e4m3(f).__x; }
__device__ inline float fp82f(unsigned char b) {
    __hip_fp8_e4m3 h; h.__x = b; return (float)h;
}
__device__ inline unsigned int pack_fp8x4(float a, float b, float c, float d) {
    return (unsigned)f2fp8(a) | ((unsigned)f2fp8(b) << 8) |
           ((unsigned)f2fp8(c) << 16) | ((unsigned)f2fp8(d) << 24);
}

// ---------------------------------------------------------------------------
// Weight prep: sage + head weights fp32 -> fp8 [n][k].  Zeroes deg/total.
// ---------------------------------------------------------------------------
__global__ __launch_bounds__(256) void k_prep(
    const float* __restrict__ Wl, const float* __restrict__ Wr,
    const float* __restrict__ W0,
    unsigned char* __restrict__ Wt8, unsigned char* __restrict__ Wh8,
    int* __restrict__ deg, int* __restrict__ total)
{
    int t = blockIdx.x * 256 + threadIdx.x;
    const int total_sage = 3 * 256 * 512;
    if (t < total_sage) {
        int l = t >> 17;
        int rem = t & 131071;
        int n = rem >> 9;
        int k = rem & 511;
        const float* Wsrc = (k < 256) ? (Wl + (size_t)l * 65536)
                                      : (Wr + (size_t)l * 65536);
        Wt8[t] = f2fp8(Wsrc[(k & 255) * 256 + n]);
    } else {
        int u = t - total_sage;
        if (u < 65536) {
            int n = u >> 8, k = u & 255;
            Wh8[u] = f2fp8(W0[k * 256 + n]);
        }
    }
    if (t < N_NODES) deg[t] = 0;
    if (t == 0) *total = 0;
}

// ---------------------------------------------------------------------------
// Init: x0 in fp8 (row = 256B: [emb 0..127 | attr 128..255]).
// 16 thr/node x 8 cols, uint2 stores.  Tail ranges: output tail + histogram.
// ---------------------------------------------------------------------------
__global__ __launch_bounds__(256) void k_init(
    const float* __restrict__ node_attr,
    const float* __restrict__ node_emb,
    const float* __restrict__ net_W, const float* __restrict__ net_b,
    const float* __restrict__ dev_W, const float* __restrict__ dev_b,
    const float* __restrict__ pin_emb,
    const int*   __restrict__ node_type,
    const float* __restrict__ y, const float* __restrict__ b1,
    const int*   __restrict__ edge_index, int* __restrict__ deg,
    float* __restrict__ out,
    unsigned char* __restrict__ x)
{
    int t = blockIdx.x * 256 + threadIdx.x;
    if (t < N_NODES * 16) {
        int n  = t >> 4;
        int c8 = (t & 15) * 8;
        int ty = node_type[n];
        float4 e0 = *(const float4*)(node_emb + ty * NE + c8);
        float4 e1 = *(const float4*)(node_emb + ty * NE + c8 + 4);
        float4 a0, a1;
        if (ty == 0 || ty == 1) {
            const float* W = (ty == 0) ? net_W : dev_W;
            const float* b = (ty == 0) ? net_b : dev_b;
            a0 = *(const float4*)(b + c8);
            a1 = *(const float4*)(b + c8 + 4);
            const float* ar = node_attr + (size_t)n * 17;
            #pragma unroll
            for (int k = 0; k < 17; ++k) {
                float av = ar[k];
                float4 w0 = *(const float4*)(W + k * NE + c8);
                float4 w1 = *(const float4*)(W + k * NE + c8 + 4);
                a0.x += av * w0.x; a0.y += av * w0.y;
                a0.z += av * w0.z; a0.w += av * w0.w;
                a1.x += av * w1.x; a1.y += av * w1.y;
                a1.z += av * w1.z; a1.w += av * w1.w;
            }
        } else if (ty == 2) {
            int idx = (int)node_attr[(size_t)n * 17];
            a0 = *(const float4*)(pin_emb + idx * NE + c8);
            a1 = *(const float4*)(pin_emb + idx * NE + c8 + 4);
        } else {
            a0.x = a0.y = a0.z = a0.w = 0.0f;
            a1 = a0;
        }
        uint2 ev = {pack_fp8x4(e0.x, e0.y, e0.z, e0.w),
                    pack_fp8x4(e1.x, e1.y, e1.z, e1.w)};
        uint2 av = {pack_fp8x4(a0.x, a0.y, a0.z, a0.w),
                    pack_fp8x4(a1.x, a1.y, a1.z, a1.w)};
        *(uint2*)(x + (size_t)n * 256 + c8)       = ev;
        *(uint2*)(x + (size_t)n * 256 + 128 + c8) = av;
    } else if (t < N_NODES * 17) {
        int n = t - N_NODES * 16;
        float y0 = y[(size_t)n * 2 + 0];
        float y1 = y[(size_t)n * 2 + 1];
        out[n] = b1[0];
        out[N_NODES + n] = (float)(int)y1;
        out[2 * N_NODES + 2 * n + 0] = y0;
        out[2 * N_NODES + 2 * n + 1] = y1;
    } else {
        int e = t - N_NODES * 17;
        if (e < N_EDGES) atomicAdd(&deg[edge_index[N_EDGES + e]], 1);
    }
}

// ---------------------------------------------------------------------------
// CSR build: scan-free chunk allocation -> fill
// ---------------------------------------------------------------------------
__global__ __launch_bounds__(256) void k_alloc(
    const int* __restrict__ deg, int* __restrict__ off,
    int* __restrict__ cursor, int* __restrict__ total)
{
    int n = blockIdx.x * 256 + threadIdx.x;
    int lane = threadIdx.x & 63;
    int d = (n < N_NODES) ? deg[n] : 0;
    int incl = d;
    #pragma unroll
    for (int o = 1; o < 64; o <<= 1) {
        int v = __shfl_up(incl, o, 64);
        if (lane >= o) incl += v;
    }
    int wtot = __shfl(incl, 63, 64);
    int base = 0;
    if (lane == 63) base = atomicAdd(total, wtot);
    base = __shfl(base, 63, 64);
    if (n < N_NODES) {
        int o = base + incl - d;
        off[n] = o;
        cursor[n] = o;
    }
}

__global__ __launch_bounds__(256) void k_fill(
    const int* __restrict__ edge_index, int* __restrict__ cursor,
    int* __restrict__ slots)
{
    int e = blockIdx.x * 256 + threadIdx.x;
    if (e >= N_EDGES) return;
    int s = edge_index[e];
    int d = edge_index[N_EDGES + e];
    int slot = atomicAdd(&cursor[d], 1);
    slots[slot] = s;
}

// ---------------------------------------------------------------------------
// Gather-mean over fp8 rows (256B): 4 nodes/wave, 16 lanes x 16B, fp32 acc.
// ---------------------------------------------------------------------------
__global__ __launch_bounds__(256) void k_aggregate(
    const unsigned char* __restrict__ x,
    const int* __restrict__ off, const int* __restrict__ deg,
    const int* __restrict__ slots,
    unsigned char* __restrict__ agg)
{
    int g = blockIdx.x * 256 + threadIdx.x;
    int wid = g >> 6;
    int lane = g & 63;
    int sub = lane >> 4;
    int l16 = lane & 15;
    int n = wid * 4 + sub;
    bool active = n < N_NODES;
    int o = 0, d = 0;
    if (active) { o = off[n]; d = deg[n]; }
    float acc[16];
    #pragma unroll
    for (int i = 0; i < 16; ++i) acc[i] = 0.0f;
    for (int p = 0; p < d; ++p) {
        int src = slots[o + p];
        uint4 v = *(const uint4*)(x + (size_t)src * 256 + l16 * 16);
        unsigned int uu[4] = {v.x, v.y, v.z, v.w};
        #pragma unroll
        for (int j = 0; j < 4; ++j)
            #pragma unroll
            for (int b = 0; b < 4; ++b)
                acc[j * 4 + b] += fp82f((uu[j] >> (8 * b)) & 0xffu);
    }
    if (active) {
        float rs = 1.0f / fmaxf((float)d, 1.0f);
        uint4 ov;
        ov.x = pack_fp8x4(acc[0] * rs,  acc[1] * rs,  acc[2] * rs,  acc[3] * rs);
        ov.y = pack_fp8x4(acc[4] * rs,  acc[5] * rs,  acc[6] * rs,  acc[7] * rs);
        ov.z = pack_fp8x4(acc[8] * rs,  acc[9] * rs,  acc[10] * rs, acc[11] * rs);
        ov.w = pack_fp8x4(acc[12] * rs, acc[13] * rs, acc[14] * rs, acc[15] * rs);
        *(uint4*)(agg + (size_t)n * 256 + l16 * 16) = ov;
    }
}

// ---------------------------------------------------------------------------
// SAGE layer, fp8 MFMA (R10 skeleton).  SWIZZLE FIX vs R15: key (r>>1)&3
// (r&3 correlated with the bank-row bit r&1 -> 4-way conflict, 10.4M/disp;
// (r>>1)&3 is drawn from disjoint bits -> 16 distinct bank-pairs per
// 64-lane ds_read_b64 = 2-way = free).
// 512 thr = 8 waves x 32 cols; tile 128x256, BK=64B; 3-buffer LDS,
// single barrier/step, steady vmcnt(1) ([stage(s), B(s)x4, stage(s+1)]).
// Out = relu([Agg8|X8] @ Wt8^T + bias) -> fp8 (row 256B).
// ---------------------------------------------------------------------------
__global__ __launch_bounds__(512, 4) void k_sage(
    const unsigned char* __restrict__ Agg8,
    const unsigned char* __restrict__ X8,
    const unsigned char* __restrict__ Wt8,
    const float* __restrict__ bias,
    unsigned char* __restrict__ Out)
{
    __shared__ char smem[32768];    // staging 3x8KB; epilogue tile reuse

    const int tid  = threadIdx.x;
    const int w    = tid >> 6, lane = tid & 63;
    const int l15  = lane & 15, lg = lane >> 4;
    const int row0 = blockIdx.x * 128;

    f32x4 acc[8][2];
    #pragma unroll
    for (int i = 0; i < 8; ++i)
        #pragma unroll
        for (int n = 0; n < 2; ++n) acc[i][n] = (f32x4)0.0f;

    // staging: 4 thr/row x 16B; row = tid>>2 (0..127), c16 = tid&3
    const int srow = tid >> 2;
    const int c16s = tid & 3;
    int sgrow = row0 + srow; if (sgrow >= N_NODES) sgrow = N_NODES - 1;
    const int skey = (srow >> 1) & 3;

    auto stage = [&](int s) {
        const int b = s % 3;
        const unsigned char* base = (s < 4) ? Agg8 : X8;
        int k0 = (s & 3) * 64;
        const unsigned char* gp = base + (size_t)sgrow * 256 + k0
                                + ((c16s ^ skey) << 4);         // inverse swizzle
        const char* lp = smem + b * 8192 + tid * 16;            // linear dest
        __builtin_amdgcn_global_load_lds(
            (const __attribute__((address_space(1))) void*)gp,
            (__attribute__((address_space(3))) void*)lp, 16, 0, 0);
    };

    auto loadB = [&](int s, i64v (&bb)[2][2]) {
        #pragma unroll
        for (int h = 0; h < 2; ++h)
            #pragma unroll
            for (int n = 0; n < 2; ++n) {
                int c = w * 32 + n * 16 + l15;
                bb[h][n] = *(const i64v*)(Wt8 + (size_t)c * 512 + s * 64
                                          + h * 32 + lg * 8);
            }
    };

    auto do_step = [&](int s, bool last, i64v (&bcur)[2][2], i64v (&bnxt)[2][2]) {
        const int b = s % 3;
        if (last) asm volatile("s_waitcnt vmcnt(0)" ::: "memory");
        else      asm volatile("s_waitcnt vmcnt(1)" ::: "memory");
        __builtin_amdgcn_sched_barrier(0);
        __builtin_amdgcn_s_barrier();
        __builtin_amdgcn_sched_barrier(0);
        if (!last) loadB(s + 1, bnxt);          // B prefetch for next step
        if (s + 2 < 8) stage(s + 2);            // 2-step-ahead A staging
        #pragma unroll
        for (int h = 0; h < 2; ++h) {
            const int c8 = h * 4 + lg;          // 8B chunk index 0..7
            #pragma unroll
            for (int i = 0; i < 8; ++i) {
                int r = i * 16 + l15;
                i64v a = *(const i64v*)(smem + b * 8192 + r * 64
                            + ((((c8 >> 1) ^ ((r >> 1) & 3)) << 4)
                               | ((c8 & 1) << 3)));
                acc[i][0] = __builtin_amdgcn_mfma_f32_16x16x32_fp8_fp8(
                    a, bcur[h][0], acc[i][0], 0, 0, 0);
                acc[i][1] = __builtin_amdgcn_mfma_f32_16x16x32_fp8_fp8(
                    a, bcur[h][1], acc[i][1], 0, 0, 0);
            }
        }
    };

    i64v b0[2][2], b1r[2][2];
    loadB(0, b0);       // queue: [B0 x4, st0, st1] -> vmcnt(1) at step 0 ok
    stage(0);
    stage(1);
    do_step(0, false, b0, b1r);
    do_step(1, false, b1r, b0);
    do_step(2, false, b0, b1r);
    do_step(3, false, b1r, b0);
    do_step(4, false, b0, b1r);
    do_step(5, false, b1r, b0);
    do_step(6, false, b0, b1r);
    do_step(7, true,  b1r, b0);

    __syncthreads();   // all waves done with staging before epilogue reuse
    unsigned char* lo = (unsigned char*)smem;     // 64x256 fp8 = 16KB half
    #pragma unroll
    for (int hh = 0; hh < 2; ++hh) {
        #pragma unroll
        for (int n = 0; n < 2; ++n) {
            int c = w * 32 + n * 16 + l15;
            float bv = bias[c];
            #pragma unroll
            for (int i2 = 0; i2 < 4; ++i2) {
                int i = hh * 4 + i2;
                #pragma unroll
                for (int r = 0; r < 4; ++r) {
                    int rl = i2 * 16 + lg * 4 + r;
                    lo[rl * 256 + c] = f2fp8(fmaxf(acc[i][n][r] + bv, 0.0f));
                }
            }
        }
        __syncthreads();
        #pragma unroll
        for (int q = 0; q < 2; ++q) {
            int chunk = tid + q * 512;      // 1024 x 16B = 64 rows x 256B
            int rl = chunk >> 4, cc = chunk & 15;
            int grow = row0 + hh * 64 + rl;
            if (grow < N_NODES)
                *(uint4*)(Out + (size_t)grow * 256 + cc * 16) =
                    *(const uint4*)((const char*)smem + rl * 256 + cc * 16);
        }
        __syncthreads();
    }
}

// ---------------------------------------------------------------------------
// HEAD, fp8: Pred += relu(X8 @ Wh8^T + b0) . W1  (K=256, 4 steps; same
// staging/swizzle as k_sage; Pred pre-init b1; atomicAdd partials).
// ---------------------------------------------------------------------------
__global__ __launch_bounds__(512, 4) void k_head8(
    const unsigned char* __restrict__ X8,
    const unsigned char* __restrict__ Wh8,
    const float* __restrict__ bias,
    const float* __restrict__ W1,
    float* __restrict__ Pred)
{
    __shared__ char smem[24576];    // 3x8KB staging

    const int tid  = threadIdx.x;
    const int w    = tid >> 6, lane = tid & 63;
    const int l15  = lane & 15, lg = lane >> 4;
    const int row0 = blockIdx.x * 128;

    f32x4 acc[8][2];
    #pragma unroll
    for (int i = 0; i < 8; ++i)
        #pragma unroll
        for (int n = 0; n < 2; ++n) acc[i][n] = (f32x4)0.0f;

    const int srow = tid >> 2;
    const int c16s = tid & 3;
    int sgrow = row0 + srow; if (sgrow >= N_NODES) sgrow = N_NODES - 1;
    const int skey = (srow >> 1) & 3;

    auto stage = [&](int s) {
        const int b = s % 3;
        const unsigned char* gp = X8 + (size_t)sgrow * 256 + s * 64
                                + ((c16s ^ skey) << 4);
        const char* lp = smem + b * 8192 + tid * 16;
        __builtin_amdgcn_global_load_lds(
            (const __attribute__((address_space(1))) void*)gp,
            (__attribute__((address_space(3))) void*)lp, 16, 0, 0);
    };

    auto loadB = [&](int s, i64v (&bb)[2][2]) {
        #pragma unroll
        for (int h = 0; h < 2; ++h)
            #pragma unroll
            for (int n = 0; n < 2; ++n) {
                int c = w * 32 + n * 16 + l15;
                bb[h][n] = *(const i64v*)(Wh8 + (size_t)c * 256 + s * 64
                                          + h * 32 + lg * 8);
            }
    };

    auto do_step = [&](int s, bool last, i64v (&bcur)[2][2], i64v (&bnxt)[2][2]) {
        const int b = s % 3;
        if (last) asm volatile("s_waitcnt vmcnt(0)" ::: "memory");
        else      asm volatile("s_waitcnt vmcnt(1)" ::: "memory");
        __builtin_amdgcn_sched_barrier(0);
        __builtin_amdgcn_s_barrier();
        __builtin_amdgcn_sched_barrier(0);
        if (!last) loadB(s + 1, bnxt);
        if (s + 2 < 4) stage(s + 2);
        #pragma unroll
        for (int h = 0; h < 2; ++h) {
            const int c8 = h * 4 + lg;
            #pragma unroll
            for (int i = 0; i < 8; ++i) {
                int r = i * 16 + l15;
                i64v a = *(const i64v*)(smem + b * 8192 + r * 64
                            + ((((c8 >> 1) ^ ((r >> 1) & 3)) << 4)
                               | ((c8 & 1) << 3)));
                acc[i][0] = __builtin_amdgcn_mfma_f32_16x16x32_fp8_fp8(
                    a, bcur[h][0], acc[i][0], 0, 0, 0);
                acc[i][1] = __builtin_amdgcn_mfma_f32_16x16x32_fp8_fp8(
                    a, bcur[h][1], acc[i][1], 0, 0, 0);
            }
        }
    };

    i64v b0[2][2], b1r[2][2];
    loadB(0, b0);
    stage(0);
    stage(1);
    do_step(0, false, b0, b1r);
    do_step(1, false, b1r, b0);
    do_step(2, false, b0, b1r);
    do_step(3, true,  b1r, b0);

    #pragma unroll
    for (int i = 0; i < 8; ++i) {
        float p[4];
        #pragma unroll
        for (int r = 0; r < 4; ++r) p[r] = 0.0f;
        #pragma unroll
        for (int n = 0; n < 2; ++n) {
            int cg = w * 32 + n * 16 + l15;
            float bv = bias[cg];
            float wv = W1[cg];
            #pragma unroll
            for (int r = 0; r < 4; ++r)
                p[r] += fmaxf(acc[i][n][r] + bv, 0.0f) * wv;
        }
        #pragma unroll
        for (int r = 0; r < 4; ++r) {
            float s = p[r];
            #pragma unroll
            for (int m = 1; m < 16; m <<= 1) s += __shfl_xor(s, m, 64);
            if (l15 == 0) {
                int row = row0 + i * 16 + lg * 4 + r;
                if (row < N_NODES) atomicAdd(&Pred[row], s);
            }
        }
    }
}

extern "C" void kernel_launch(void* const* d_in, const int* in_sizes, int n_in,
                              void* d_out, int out_size, void* d_ws, size_t ws_size,
                              hipStream_t stream) {
    const float* node_attr = (const float*)d_in[0];
    const float* y         = (const float*)d_in[1];
    const float* node_emb  = (const float*)d_in[2];
    const float* net_W     = (const float*)d_in[4];
    const float* net_b     = (const float*)d_in[5];
    const float* dev_W     = (const float*)d_in[6];
    const float* dev_b     = (const float*)d_in[7];
    const float* pin_emb   = (const float*)d_in[8];
    const float* sage_Wl   = (const float*)d_in[9];
    const float* sage_bl   = (const float*)d_in[10];
    const float* sage_Wr   = (const float*)d_in[11];
    const float* head_W0   = (const float*)d_in[12];
    const float* head_b0   = (const float*)d_in[13];
    const float* head_W1   = (const float*)d_in[14];
    const float* head_b1   = (const float*)d_in[15];
    const int*   node_type = (const int*)d_in[16];
    const int*   edge_idx  = (const int*)d_in[18];
    float* out = (float*)d_out;

    const size_t x8b = (size_t)N_NODES * 256;       // fp8 row bytes
    char* p = (char*)d_ws;
    unsigned char* x0   = (unsigned char*)p;  p += x8b;
    unsigned char* x1   = (unsigned char*)p;  p += x8b;
    unsigned char* agg8 = (unsigned char*)p;  p += x8b;
    unsigned char* Wt8  = (unsigned char*)p;  p += (size_t)3 * 256 * 512;
    unsigned char* Wh8  = (unsigned char*)p;  p += (size_t)256 * 256;
    int* deg    = (int*)p; p += N_NODES * 4;
    int* off    = (int*)p; p += N_NODES * 4;
    int* cursor = (int*)p; p += N_NODES * 4;
    int* slots  = (int*)p; p += N_EDGES * 4;
    int* total  = (int*)p; p += 16;

    k_prep<<<(3 * 131072 + 65536 + 255) / 256, 256, 0, stream>>>(
        sage_Wl, sage_Wr, head_W0, Wt8, Wh8, deg, total);
    k_init<<<(N_NODES * 17 + N_EDGES + 255) / 256, 256, 0, stream>>>(
        node_attr, node_emb, net_W, net_b, dev_W, dev_b, pin_emb, node_type,
        y, head_b1, edge_idx, deg, out, x0);
    k_alloc<<<(N_NODES + 255) / 256, 256, 0, stream>>>(deg, off, cursor, total);
    k_fill<<<(N_EDGES + 255) / 256, 256, 0, stream>>>(edge_idx, cursor, slots);

    const int agg_grid  = (N_NODES / 4 * 64 + 255) / 256;
    const int gemm_grid = (N_NODES + 127) / 128;
    // layer 1
    k_aggregate<<<agg_grid, 256, 0, stream>>>(x0, off, deg, slots, agg8);
    k_sage<<<gemm_grid, 512, 0, stream>>>(agg8, x0, Wt8, sage_bl, x1);
    // layer 2
    k_aggregate<<<agg_grid, 256, 0, stream>>>(x1, off, deg, slots, agg8);
    k_sage<<<gemm_grid, 512, 0, stream>>>(agg8, x1, Wt8 + 131072,
                                          sage_bl + HID, x0);
    // layer 3
    k_aggregate<<<agg_grid, 256, 0, stream>>>(x0, off, deg, slots, agg8);
    k_sage<<<gemm_grid, 512, 0, stream>>>(agg8, x0, Wt8 + 262144,
                                          sage_bl + 2 * HID, x1);
    // head
    k_head8<<<gemm_grid, 512, 0, stream>>>(x1, Wh8, head_b0, head_W1, out);
}